// Round 3
// baseline (1025.360 us; speedup 1.0000x reference)
//
#include <hip/hip_runtime.h>
#include <cstdint>

#define D_MODEL 1024
#define N_EXP   16
#define D_FF    4096
#define NTOK    4096      // B*T
#define NSEL    8192      // NTOK * k

typedef uint16_t u16;
typedef __bf16    bf16x8 __attribute__((ext_vector_type(8)));
typedef uint16_t  u16x8  __attribute__((ext_vector_type(8)));
typedef float     f32x4  __attribute__((ext_vector_type(4)));
typedef uint32_t  u32x2  __attribute__((ext_vector_type(2)));

__device__ __forceinline__ u16 f2bf(float x) {
    union { float f; uint32_t i; } c; c.f = x;
    uint32_t i = c.i + 0x7fffu + ((c.i >> 16) & 1u);   // RNE (finite data)
    return (u16)(i >> 16);
}

// packed f32x2 -> bf16x2 (RNE), 1 instruction for 2 elements
__device__ __forceinline__ uint32_t cvtpk(float lo, float hi) {
    uint32_t r;
    asm("v_cvt_pk_bf16_f32 %0, %1, %2" : "=v"(r) : "v"(lo), "v"(hi));
    return r;
}

// async global->LDS, 16B per lane; lds base must be wave-uniform
#define ASYNC16(gp, lp) __builtin_amdgcn_global_load_lds( \
    (__attribute__((address_space(1))) void*)(gp),        \
    (__attribute__((address_space(3))) void*)(lp), 16, 0, 0)

// ---------------- gating: one wave per token, exact fp32 (unchanged) --------
__global__ void gate_kernel(const float* __restrict__ x, const float* __restrict__ Wg,
                            int* __restrict__ tok_idx, float* __restrict__ tok_w,
                            int* __restrict__ counts)
{
    const int lane = threadIdx.x & 63;
    const int t = blockIdx.x * 4 + (threadIdx.x >> 6);
    const float* xr = x + (size_t)t * D_MODEL;
    float acc[N_EXP];
    #pragma unroll
    for (int e = 0; e < N_EXP; e++) acc[e] = 0.f;
    for (int d = lane; d < D_MODEL; d += 64) {
        float xv = xr[d];
        const float* wr = Wg + d * N_EXP;
        #pragma unroll
        for (int e = 0; e < N_EXP; e++) acc[e] += xv * wr[e];
    }
    #pragma unroll
    for (int e = 0; e < N_EXP; e++) {
        float v = acc[e];
        #pragma unroll
        for (int o = 32; o > 0; o >>= 1) v += __shfl_xor(v, o, 64);
        acc[e] = v;
    }
    if (lane == 0) {
        int i0 = 0; float v0 = acc[0];
        #pragma unroll
        for (int e = 1; e < N_EXP; e++) if (acc[e] > v0) { v0 = acc[e]; i0 = e; }
        int i1 = (i0 == 0) ? 1 : 0; float v1 = -3.0e38f;
        #pragma unroll
        for (int e = 0; e < N_EXP; e++) if (e != i0 && acc[e] > v1) { v1 = acc[e]; i1 = e; }
        float e1  = __expf(v1 - v0);
        float inv = 1.f / (1.f + e1);
        tok_idx[2 * t] = i0;  tok_idx[2 * t + 1] = i1;
        tok_w[2 * t] = inv;   tok_w[2 * t + 1] = e1 * inv;
        atomicAdd(&counts[i0], 1);
        atomicAdd(&counts[i1], 1);
    }
}

__global__ void scan_kernel(const int* __restrict__ counts, int* __restrict__ offsets,
                            int* __restrict__ cursors)
{
    if (threadIdx.x == 0) {
        int s = 0;
        #pragma unroll
        for (int e = 0; e < N_EXP; e++) { offsets[e] = s; cursors[e] = s; s += counts[e]; }
        offsets[N_EXP] = s;   // == NSEL
    }
}

__global__ void scatter_kernel(const int* __restrict__ tok_idx, const float* __restrict__ tok_w,
                               int* __restrict__ cursors, int* __restrict__ perm_token,
                               float* __restrict__ perm_w)
{
    const int t = blockIdx.x * 256 + threadIdx.x;
    #pragma unroll
    for (int j = 0; j < 2; j++) {
        int e = tok_idx[2 * t + j];
        int slot = atomicAdd(&cursors[e], 1);
        perm_token[slot] = t;
        perm_w[slot] = tok_w[2 * t + j];
    }
}

// ---------------- gather + fp32->bf16 convert of A (x permuted) ----------------
__global__ void gatherA_kernel(const float* __restrict__ x, const int* __restrict__ perm_token,
                               u16* __restrict__ Abf)
{
    const int slot = blockIdx.x;
    const int t = perm_token[slot];
    const float* src = x + (size_t)t * D_MODEL;
    u16* dst = Abf + (size_t)slot * D_MODEL;
    const int d = threadIdx.x * 4;
    f32x4 v = *(const f32x4*)(src + d);
    u32x2 o;
    o.x = cvtpk(v[0], v[1]);
    o.y = cvtpk(v[2], v[3]);
    *(u32x2*)(dst + d) = o;
}

// ------------- W [e][K][N] fp32 -> Wt [e][N][K] bf16 (64x64 LDS tiles) -------
// HBM-bound (~768 MB total for both weights); RNE bf16 => numerics identical
// to the previous in-GEMM conversion.
__global__ __launch_bounds__(256)
void transpose_kernel(const float* __restrict__ W, u16* __restrict__ Wt, int K, int N)
{
    __shared__ u16 Tl[64 * 72];        // [n][k], stride 72 u16 = 144 B (16B-aligned rows)
    const int e  = blockIdx.z;
    const int n0 = blockIdx.x * 64, k0 = blockIdx.y * 64;
    const int tid = threadIdx.x;
    const float* src = W + (size_t)e * K * N + (size_t)k0 * N + n0;
    u16* dst = Wt + (size_t)e * N * K + (size_t)n0 * K + k0;

    const int kl = tid >> 4;           // 0..15
    const int nl = (tid & 15) * 4;
    #pragma unroll
    for (int p = 0; p < 4; p++) {
        const int kk = p * 16 + kl;
        f32x4 v = *(const f32x4*)(src + (size_t)kk * N + nl);
        #pragma unroll
        for (int j = 0; j < 4; j++) Tl[(nl + j) * 72 + kk] = f2bf(v[j]);
    }
    __syncthreads();
    const int nr = tid >> 3;           // 0..31
    const int ks = (tid & 7) * 8;
    #pragma unroll
    for (int p = 0; p < 2; p++) {
        const int nn = p * 32 + nr;
        u16x8 o = *(const u16x8*)(&Tl[nn * 72 + ks]);
        *(u16x8*)(dst + (size_t)nn * K + ks) = o;
    }
}

// ---------------- grouped GEMM, 128x128 tile, BK=32, 4 waves -----------------
// Both operands bf16, staged via global_load_lds w=16 with source-side octet
// swizzle (LDS dest linear; rule #21).  m97 structure: 4 ASYNC16 + 8
// ds_read_b128 + 16 MFMA per thread-step, double-buffered, ONE barrier/step.
// Chunked XCD remap (bijective; totals %8==0), expert-major work order so
// same-expert blocks share one XCD's L2 (A-panel + B-panel reuse).
// KSPLIT>1 (GEMM2): fp32 atomicAdd into out[token] fuses the combine kernel.
template<bool SWISH, int KSPLIT>
__global__ __launch_bounds__(256, 4)
void gemm_kernel(const u16* __restrict__ A, const u16* __restrict__ Bt,
                 const float* __restrict__ bias, const int* __restrict__ offsets,
                 const int* __restrict__ perm_token, const float* __restrict__ perm_w,
                 u16* __restrict__ Hout, float* __restrict__ Yout,
                 int K, int N)
{
    // ---- chunked XCD remap: linear id L -> work id wid; decode n fastest ----
    const int gx = gridDim.x, gy = gridDim.y;
    const int L = blockIdx.x + gx * (blockIdx.y + gy * blockIdx.z);
    const int total = gx * gy * gridDim.z;      // divisible by 8
    const int wid = (L & 7) * (total >> 3) + (L >> 3);
    const int nt  = wid % gx;
    const int rem = wid / gx;
    const int mt  = rem % gy;
    const int zz  = rem / gy;

    const int e   = zz & (N_EXP - 1);
    const int ks  = zz >> 4;
    const int off = offsets[e];
    const int cnt = offsets[e + 1] - off;
    const int m0  = mt * 128;
    if (m0 >= cnt) return;
    const int n0  = nt * 128;
    const int kbase  = ks * (K / KSPLIT);
    const int ksteps = (K / KSPLIT) / 32;

    __shared__ u16 Alds[2][128 * 32];   // [m][k], octet-swizzled via source
    __shared__ u16 Blds[2][128 * 32];   // [n][k], octet-swizzled via source

    const int tid  = threadIdx.x;
    const int lane = tid & 63;
    const int w    = tid >> 6;
    const int wm   = w & 1;
    const int wn   = w >> 1;

    // --- staging: wave w covers rows w*16..+15 (and +64); lane&3 = octet slot ---
    const int srow = w * 16 + (lane >> 2);
    const int oS   = (lane & 3) ^ ((srow >> 1) & 3) ^ ((srow >> 3) & 3); // swz(r+64)==swz(r)
    int rA = m0 + srow;      if (rA > cnt - 1) rA = cnt - 1;
    int rB = m0 + srow + 64; if (rB > cnt - 1) rB = cnt - 1;
    const u16* ap0 = A + (size_t)(off + rA) * K + oS * 8;
    const u16* ap1 = A + (size_t)(off + rB) * K + oS * 8;
    const u16* bp0 = Bt + ((size_t)e * N + n0 + srow) * K + oS * 8;
    const u16* bp1 = Bt + ((size_t)e * N + n0 + srow + 64) * K + oS * 8;

    // --- fragment read offsets (matching swizzle) ---
    const int q = lane >> 4;
    int a_rd[4];
    #pragma unroll
    for (int mi = 0; mi < 4; mi++) {
        const int r   = wm * 64 + mi * 16 + (lane & 15);
        const int oct = q ^ ((r >> 1) & 3) ^ ((r >> 3) & 3);
        a_rd[mi] = r * 32 + oct * 8;
    }
    const int fbase = wn * 64 + (lane & 15);
    int b_rd[4];
    #pragma unroll
    for (int ni = 0; ni < 4; ni++) {
        const int f   = fbase + ni * 16;
        const int oct = q ^ ((f >> 1) & 3) ^ ((f >> 3) & 3);
        b_rd[ni] = f * 32 + oct * 8;
    }

    f32x4 acc[4][4] = {};

    // ---- prologue: stage tile 0 into buf 0 ----
    ASYNC16(ap0 + kbase, &Alds[0][w * 512]);
    ASYNC16(ap1 + kbase, &Alds[0][(w + 4) * 512]);
    ASYNC16(bp0 + kbase, &Blds[0][w * 512]);
    ASYNC16(bp1 + kbase, &Blds[0][(w + 4) * 512]);
    __syncthreads();

    int cur = 0;
    for (int i = 0; i < ksteps; ++i) {
        const bool has_next = (i + 1 < ksteps);
        if (has_next) {
            const int ktn = kbase + (i + 1) * 32;
            ASYNC16(ap0 + ktn, &Alds[cur ^ 1][w * 512]);
            ASYNC16(ap1 + ktn, &Alds[cur ^ 1][(w + 4) * 512]);
            ASYNC16(bp0 + ktn, &Blds[cur ^ 1][w * 512]);
            ASYNC16(bp1 + ktn, &Blds[cur ^ 1][(w + 4) * 512]);
        }

        u16x8 af[4], bfr[4];
        #pragma unroll
        for (int mi = 0; mi < 4; mi++) af[mi] = *(const u16x8*)(&Alds[cur][a_rd[mi]]);
        #pragma unroll
        for (int ni = 0; ni < 4; ni++) bfr[ni] = *(const u16x8*)(&Blds[cur][b_rd[ni]]);
        #pragma unroll
        for (int mi = 0; mi < 4; mi++)
            #pragma unroll
            for (int ni = 0; ni < 4; ni++)
                acc[mi][ni] = __builtin_amdgcn_mfma_f32_16x16x32_bf16(
                    __builtin_bit_cast(bf16x8, af[mi]),
                    __builtin_bit_cast(bf16x8, bfr[ni]),
                    acc[mi][ni], 0, 0, 0);

        if (has_next) {
            __syncthreads();    // drains vmcnt(0): next tile resident; cur reads done
            cur ^= 1;
        }
    }

    // epilogue: C/D layout col=lane&15, row=(lane>>4)*4+reg  [m89-verified]
    const int rowq = (lane >> 4) * 4;
    #pragma unroll
    for (int mi = 0; mi < 4; mi++) {
        #pragma unroll
        for (int r = 0; r < 4; r++) {
            const int m = m0 + wm * 64 + mi * 16 + rowq + r;
            if (m < cnt) {
                const size_t gm = (size_t)(off + m);
                if constexpr (SWISH) {
                    #pragma unroll
                    for (int ni = 0; ni < 4; ni++) {
                        const int gn = n0 + fbase + ni * 16;
                        float c = acc[mi][ni][r] + bias[(size_t)e * N + gn];
                        float s = c / (1.f + __expf(-c));   // swish
                        Hout[gm * (size_t)N + gn] = f2bf(s);
                    }
                } else {
                    const int   tok = perm_token[gm];
                    const float pw  = perm_w[gm];
                    float* orow = Yout + (size_t)tok * N;
                    #pragma unroll
                    for (int ni = 0; ni < 4; ni++) {
                        const int gn = n0 + fbase + ni * 16;
                        float c = acc[mi][ni][r];
                        if (ks == 0) c += bias[(size_t)e * N + gn];
                        atomicAdd(&orow[gn], c * pw);   // fused combine, split-K sum
                    }
                }
            }
        }
    }
}

extern "C" void kernel_launch(void* const* d_in, const int* in_sizes, int n_in,
                              void* d_out, int out_size, void* d_ws, size_t ws_size,
                              hipStream_t stream)
{
    const float* x  = (const float*)d_in[0];
    const float* W1 = (const float*)d_in[1];
    const float* b1 = (const float*)d_in[2];
    const float* W2 = (const float*)d_in[3];
    const float* b2 = (const float*)d_in[4];
    const float* Wg = (const float*)d_in[5];
    // d_in[6] = k (always 2)

    char* ws = (char*)d_ws;
    int*   counts     = (int*)(ws);                      // 64 B
    int*   offsets    = (int*)(ws + 64);                 // 17 ints
    int*   cursors    = (int*)(ws + 192);                // 16 ints
    int*   tok_idx    = (int*)(ws + 256);                // 8192 ints
    float* tok_w      = (float*)(ws + 256 + 32768);      // 8192 f32
    int*   perm_token = (int*)(ws + 256 + 2 * 32768);    // 8192 ints
    float* perm_w     = (float*)(ws + 256 + 3 * 32768);  // 8192 f32
    u16*   h   = (u16*)(ws + 262144);                              // 64 MB bf16
    u16*   Abf = (u16*)(ws + 262144 + (size_t)NSEL * D_FF * 2);    // 16 MB bf16
    u16*   W1t = (u16*)(ws + 262144 + (size_t)NSEL * D_FF * 2
                              + (size_t)NSEL * D_MODEL * 2);       // 128 MB bf16
    u16*   W2t = W1t;   // aliased: W2 transposed AFTER GEMM1 (stream-serial)
    // total ws needed ~= 208.3 MiB

    hipMemsetAsync(counts, 0, 64, stream);
    hipMemsetAsync(d_out, 0, out_size, stream);   // atomic-accumulated output

    // W1 [e][1024][4096] -> W1t [e][4096][1024]
    transpose_kernel<<<dim3(D_FF / 64, D_MODEL / 64, N_EXP), dim3(256), 0, stream>>>(
        W1, W1t, D_MODEL, D_FF);

    gate_kernel<<<dim3(NTOK / 4), dim3(256), 0, stream>>>(x, Wg, tok_idx, tok_w, counts);
    scan_kernel<<<dim3(1), dim3(64), 0, stream>>>(counts, offsets, cursors);
    scatter_kernel<<<dim3(NTOK / 256), dim3(256), 0, stream>>>(tok_idx, tok_w, cursors,
                                                               perm_token, perm_w);
    gatherA_kernel<<<dim3(NSEL), dim3(256), 0, stream>>>(x, perm_token, Abf);

    gemm_kernel<true, 1><<<dim3(32, 64, 16), dim3(256), 0, stream>>>(
        Abf, W1t, b1, offsets, nullptr, nullptr, h, nullptr, D_MODEL, D_FF);

    // W2 [e][4096][1024] -> W2t [e][1024][4096]  (over W1t, now dead)
    transpose_kernel<<<dim3(D_MODEL / 64, D_FF / 64, N_EXP), dim3(256), 0, stream>>>(
        W2, W2t, D_FF, D_MODEL);

    gemm_kernel<false, 4><<<dim3(8, 64, 16 * 4), dim3(256), 0, stream>>>(
        h, W2t, b2, offsets, perm_token, perm_w, nullptr, (float*)d_out, D_FF, D_MODEL);
}